// Round 1
// baseline (542.475 us; speedup 1.0000x reference)
//
#include <hip/hip_runtime.h>

typedef unsigned short u16;
typedef __bf16 bf16x8 __attribute__((ext_vector_type(8)));
typedef float f32x4 __attribute__((ext_vector_type(4)));
typedef unsigned short u16x8 __attribute__((ext_vector_type(8)));
typedef unsigned short u16x4 __attribute__((ext_vector_type(4)));

#define NBATCH 32
#define NTOK   257
#define DMODEL 1024
#define NHEAD  16
#define HDIM   64
#define DMLP   4096
#define MTOK   (NBATCH*NTOK)   /* 8224 */
#define MPAD   8320            /* 65*128 */
#define QSCALE 0.125f

__device__ __forceinline__ u16 f2bf(float f){
    unsigned int u = __float_as_uint(f);
    u = u + 0x7fffu + ((u >> 16) & 1u);   // RNE
    return (u16)(u >> 16);
}

__device__ __forceinline__ f32x4 mfma16(bf16x8 a, bf16x8 b, f32x4 c){
    return __builtin_amdgcn_mfma_f32_16x16x32_bf16(a, b, c, 0, 0, 0);
}

__device__ __forceinline__ void gload16(const void* g, void* l){
    __builtin_amdgcn_global_load_lds(
        (const __attribute__((address_space(1))) unsigned int*)g,
        (__attribute__((address_space(3))) unsigned int*)l, 16, 0, 0);
}

__device__ __forceinline__ float waveSum64(float v){
    #pragma unroll
    for (int d = 1; d < 64; d <<= 1) v += __shfl_xor(v, d);
    return v;
}

// ---------------- fp32 -> bf16 weight convert (n multiple of 1024) -------
__global__ __launch_bounds__(256) void cvt_f2bf(const float* __restrict__ s,
                                                u16* __restrict__ d){
    size_t i = ((size_t)blockIdx.x*256 + threadIdx.x)*4;
    float4 v = *(const float4*)(s + i);
    u16x4 o = { f2bf(v.x), f2bf(v.y), f2bf(v.z), f2bf(v.w) };
    *(u16x4*)(d + i) = o;
}

// ---------------- LayerNorm: fp32 in -> bf16 out, one block per row ------
__global__ __launch_bounds__(256) void ln_kernel(const float* __restrict__ x,
                                                 const float* __restrict__ w,
                                                 const float* __restrict__ b,
                                                 u16* __restrict__ y){
    int row = blockIdx.x, tid = threadIdx.x;
    float4 v = ((const float4*)(x + (size_t)row*DMODEL))[tid];
    float s = v.x + v.y + v.z + v.w;
    s = waveSum64(s);
    __shared__ float red[8];
    int wv = tid >> 6;
    if ((tid & 63) == 0) red[wv] = s;
    __syncthreads();
    float mean = (red[0]+red[1]+red[2]+red[3]) * (1.0f/1024.0f);
    float dx = v.x-mean, dy = v.y-mean, dz = v.z-mean, dw = v.w-mean;
    float s2 = dx*dx + dy*dy + dz*dz + dw*dw;
    s2 = waveSum64(s2);
    if ((tid & 63) == 0) red[4+wv] = s2;
    __syncthreads();
    float var = (red[4]+red[5]+red[6]+red[7]) * (1.0f/1024.0f);
    float rs = rsqrtf(var + 1e-5f);
    float4 wl = ((const float4*)w)[tid];
    float4 bl = ((const float4*)b)[tid];
    u16x4 o = { f2bf(dx*rs*wl.x + bl.x), f2bf(dy*rs*wl.y + bl.y),
                f2bf(dz*rs*wl.z + bl.z), f2bf(dw*rs*wl.w + bl.w) };
    ((u16x4*)(y + (size_t)row*DMODEL))[tid] = o;
}

// ---------------- GEMM: out[M,N] = A[M,K] @ W[N,K]^T + bias --------------
// 128x128 tile, BK=64, 4 waves (2x2), XOR-swizzled LDS, global_load_lds x16.
// EPI: 0 = (acc+bias)*scale -> bf16   (QKV)
//      1 = addsrc + acc + bias -> f32 (O-proj->h, FC2->out)
//      2 = quickgelu(acc+bias) -> bf16 (FC1)
template<int EPI>
__global__ __launch_bounds__(256) void gemm_bt(
        const u16* __restrict__ A, const u16* __restrict__ Wt,
        const float* __restrict__ bias, const float* __restrict__ addsrc,
        float* __restrict__ outf, u16* __restrict__ outb,
        int K, int Nn, int Mvalid, float scale){
    __shared__ __align__(16) u16 As[128*64];
    __shared__ __align__(16) u16 Bs[128*64];
    int tid = threadIdx.x, lane = tid & 63, w = tid >> 6;
    int wr = w >> 1, wc = w & 1;
    int m0 = blockIdx.y*128, n0 = blockIdx.x*128;
    int lrow = lane & 15, lk = lane >> 4;
    const f32x4 fz = {0.f,0.f,0.f,0.f};
    f32x4 acc[4][4];
    #pragma unroll
    for (int i = 0; i < 4; i++)
        #pragma unroll
        for (int j = 0; j < 4; j++) acc[i][j] = fz;

    const size_t Ks = (size_t)K;
    int so = w*1024 + lane*16;             // per-lane byte offset in 16KB tile
    for (int kt = 0; kt < K; kt += 64){
        #pragma unroll
        for (int i = 0; i < 4; i++){
            int o = i*4096 + so;
            int row = o >> 7;
            int gsl = ((o >> 4) & 7) ^ (row & 7);     // inverse-swizzled source
            gload16(A  + (size_t)(m0+row)*Ks + kt + gsl*8, &As[i*2048 + w*512]);
            gload16(Wt + (size_t)(n0+row)*Ks + kt + gsl*8, &Bs[i*2048 + w*512]);
        }
        __syncthreads();
        #pragma unroll
        for (int kk = 0; kk < 2; kk++){
            bf16x8 af[4], bfr[4];
            #pragma unroll
            for (int mi = 0; mi < 4; mi++){
                int row = wr*64 + mi*16 + lrow;
                int sl = (kk*4 + lk) ^ (row & 7);
                af[mi] = *(const bf16x8*)&As[row*64 + sl*8];
            }
            #pragma unroll
            for (int ni = 0; ni < 4; ni++){
                int row = wc*64 + ni*16 + lrow;
                int sl = (kk*4 + lk) ^ (row & 7);
                bfr[ni] = *(const bf16x8*)&Bs[row*64 + sl*8];
            }
            #pragma unroll
            for (int mi = 0; mi < 4; mi++)
                #pragma unroll
                for (int ni = 0; ni < 4; ni++)
                    acc[mi][ni] = mfma16(af[mi], bfr[ni], acc[mi][ni]);
        }
        __syncthreads();
    }
    // epilogue: C layout col=lane&15, row=(lane>>4)*4+reg
    #pragma unroll
    for (int mi = 0; mi < 4; mi++){
        #pragma unroll
        for (int ni = 0; ni < 4; ni++){
            int col = n0 + wc*64 + ni*16 + lrow;
            float bi = bias[col];
            #pragma unroll
            for (int r = 0; r < 4; r++){
                int row = m0 + wr*64 + mi*16 + lk*4 + r;
                if (row < Mvalid){
                    float v = acc[mi][ni][r] + bi;
                    size_t idx = (size_t)row*Nn + col;
                    if (EPI == 0){
                        outb[idx] = f2bf(v*scale);
                    } else if (EPI == 1){
                        outf[idx] = addsrc[idx] + v;
                    } else {
                        float g = v / (1.f + __expf(-1.702f*v));
                        outb[idx] = f2bf(g);
                    }
                }
            }
        }
    }
}

// ---------------- attention: one block per (b*16+h, qtile of 64 rows) ----
__global__ __launch_bounds__(256) void attn_kernel(
        const u16* __restrict__ qb, const u16* __restrict__ kb,
        const u16* __restrict__ vb, float* __restrict__ preproj,
        u16* __restrict__ ctxb, float* __restrict__ attnw){
    __shared__ __align__(16) u16 Klds[272*64];    // [krow][d], rows XOR-swizzled
    __shared__ __align__(16) u16 Vt[64*296];      // [d][krow], stride 296
    __shared__ __align__(16) u16 Plds[9*64*32];   // [kstep][qrow][koff], swz
    int tid = threadIdx.x, lane = tid & 63, w = tid >> 6;
    int bh = blockIdx.x, bq = bh >> 4, hh = bh & 15;
    int q0 = blockIdx.y*64;
    int lrow = lane & 15, lk = lane >> 4;

    size_t kvbase = ((size_t)bq*NTOK)*DMODEL + hh*HDIM;
    // stage K (swizzled rows) and V^T
    for (int c = tid; c < 2176; c += 256){
        int row = c >> 3, slot = c & 7;
        u16x8 kv = {0,0,0,0,0,0,0,0}, vv = {0,0,0,0,0,0,0,0};
        if (row < NTOK){
            kv = *(const u16x8*)(kb + kvbase + (size_t)row*DMODEL + slot*8);
            vv = *(const u16x8*)(vb + kvbase + (size_t)row*DMODEL + slot*8);
        }
        *(u16x8*)&Klds[row*64 + (slot ^ (row & 7))*8] = kv;
        #pragma unroll
        for (int j = 0; j < 8; j++) Vt[(slot*8 + j)*296 + row] = vv[j];
    }
    // zero P kstep-8 block and Vt cols 272..295
    for (int i = tid; i < 1024; i += 256) ((unsigned int*)Plds)[8*1024 + i] = 0u;
    for (int i = tid; i < 1536; i += 256){
        int d = i/24, c2 = 272 + (i - d*24);
        Vt[d*296 + c2] = 0;
    }
    // Q fragments from global (rows may overhang: finite garbage, masked later)
    int tok = bq*NTOK + q0 + w*16 + lrow;
    const u16* qp = qb + (size_t)tok*DMODEL + hh*HDIM;
    bf16x8 qf0 = *(const bf16x8*)(qp + lk*8);
    bf16x8 qf1 = *(const bf16x8*)(qp + 32 + lk*8);
    __syncthreads();

    // S = q @ k^T  (17 jtiles of 16 cols; cols 257..271 are zero-K garbage)
    f32x4 S[17];
    #pragma unroll
    for (int j = 0; j < 17; j++){
        int kcol = j*16 + lrow;
        f32x4 a = {0.f,0.f,0.f,0.f};
        bf16x8 b0 = *(const bf16x8*)&Klds[kcol*64 + ((0 + lk) ^ (kcol & 7))*8];
        a = mfma16(qf0, b0, a);
        bf16x8 b1 = *(const bf16x8*)&Klds[kcol*64 + ((4 + lk) ^ (kcol & 7))*8];
        S[j] = mfma16(qf1, b1, a);
    }
    // softmax per row (row = (lane>>4)*4 + r), reduce over 16-lane group
    #pragma unroll
    for (int r = 0; r < 4; r++){
        float mx = -1e30f;
        #pragma unroll
        for (int j = 0; j < 17; j++){
            bool valid = (j < 16) || (lrow == 0);
            mx = fmaxf(mx, valid ? S[j][r] : -1e30f);
        }
        #pragma unroll
        for (int d = 1; d < 16; d <<= 1) mx = fmaxf(mx, __shfl_xor(mx, d));
        float sum = 0.f;
        #pragma unroll
        for (int j = 0; j < 17; j++){
            bool valid = (j < 16) || (lrow == 0);
            float p = valid ? __expf(S[j][r] - mx) : 0.f;
            S[j][r] = p; sum += p;
        }
        #pragma unroll
        for (int d = 1; d < 16; d <<= 1) sum += __shfl_xor(sum, d);
        float inv = 1.f / sum;
        #pragma unroll
        for (int j = 0; j < 17; j++) S[j][r] *= inv;
    }
    // write attn_weights + P into LDS (bf16)
    #pragma unroll
    for (int r = 0; r < 4; r++){
        int rw = lk*4 + r;              // row within wave's 16
        int qrow = q0 + w*16 + rw;
        bool rowok = qrow < NTOK;
        size_t obase = ((size_t)bh*NTOK + qrow)*NTOK;
        int prow = w*16 + rw;
        #pragma unroll
        for (int j = 0; j < 17; j++){
            int col = j*16 + lrow;
            float p = S[j][r];
            if (rowok && col < NTOK) attnw[obase + col] = p;
            int kstep = col >> 5, koff = col & 31;
            int slot = (koff >> 3) ^ (prow & 3);
            Plds[kstep*2048 + prow*32 + slot*8 + (koff & 7)] = f2bf(p);
        }
    }
    __syncthreads();

    // ctx = P @ V   (9 ksteps of 32)
    f32x4 C4[4];
    #pragma unroll
    for (int n = 0; n < 4; n++) C4[n] = (f32x4){0.f,0.f,0.f,0.f};
    #pragma unroll
    for (int ks = 0; ks < 9; ks++){
        int prow = w*16 + lrow;
        int slotp = lk ^ (prow & 3);
        bf16x8 pf = *(const bf16x8*)&Plds[ks*2048 + prow*32 + slotp*8];
        #pragma unroll
        for (int n = 0; n < 4; n++){
            int d = n*16 + lrow;
            bf16x8 vf = *(const bf16x8*)&Vt[d*296 + ks*32 + lk*8];
            C4[n] = mfma16(pf, vf, C4[n]);
        }
    }
    // epilogue: pre_proj (f32, d_out) + ctx (bf16, ws)
    #pragma unroll
    for (int n = 0; n < 4; n++){
        #pragma unroll
        for (int r = 0; r < 4; r++){
            int qrow = q0 + w*16 + lk*4 + r;
            if (qrow < NTOK){
                int tok2 = bq*NTOK + qrow;
                int d = hh*HDIM + n*16 + lrow;
                float v = C4[n][r];
                preproj[(size_t)tok2*DMODEL + d] = v;
                ctxb[(size_t)tok2*DMODEL + d] = f2bf(v);
            }
        }
    }
}

// ------------------------------- launch ----------------------------------
extern "C" void kernel_launch(void* const* d_in, const int* in_sizes, int n_in,
                              void* d_out, int out_size, void* d_ws, size_t ws_size,
                              hipStream_t stream){
    const float* hidden = (const float*)d_in[0];
    const float* ln1w = (const float*)d_in[1];
    const float* ln1b = (const float*)d_in[2];
    const float* Wq   = (const float*)d_in[3];
    const float* bq   = (const float*)d_in[4];
    const float* Wk   = (const float*)d_in[5];
    const float* bk   = (const float*)d_in[6];
    const float* Wv   = (const float*)d_in[7];
    const float* bv   = (const float*)d_in[8];
    const float* Wo   = (const float*)d_in[9];
    const float* bo   = (const float*)d_in[10];
    const float* ln2w = (const float*)d_in[11];
    const float* ln2b = (const float*)d_in[12];
    const float* fc1w = (const float*)d_in[13];
    const float* fc1b = (const float*)d_in[14];
    const float* fc2w = (const float*)d_in[15];
    const float* fc2b = (const float*)d_in[16];

    float* out0 = (float*)d_out;                       // pre_proj [8224,1024]
    float* out1 = out0 + (size_t)MTOK*DMODEL;          // hidden_out
    float* out2 = out1 + (size_t)MTOK*DMODEL;          // attn_weights

    char* ws = (char*)d_ws;
    const size_t SZB = (size_t)MPAD*DMODEL*2;          // one bf16 [MPAD,1024]
    u16* xln  = (u16*)(ws);
    u16* qbuf = (u16*)(ws + SZB);
    u16* kbuf = (u16*)(ws + 2*SZB);
    u16* vbuf = (u16*)(ws + 3*SZB);
    u16* ctxb = (u16*)(ws + 4*SZB);
    u16* fc1o = qbuf;                                  // alias: qkv+ctx dead by FC1
    float* hbuf = (float*)(ws + 5*SZB);                // fp32 [MPAD,1024]
    u16* wqb = (u16*)(ws + 5*SZB + (size_t)MPAD*DMODEL*4);
    u16* wkb = wqb + 1048576;
    u16* wvb = wkb + 1048576;
    u16* wob = wvb + 1048576;
    u16* wf1 = wob + 1048576;
    u16* wf2 = wf1 + 4194304;

    // weight converts
    cvt_f2bf<<<1024, 256, 0, stream>>>(Wq, wqb);
    cvt_f2bf<<<1024, 256, 0, stream>>>(Wk, wkb);
    cvt_f2bf<<<1024, 256, 0, stream>>>(Wv, wvb);
    cvt_f2bf<<<1024, 256, 0, stream>>>(Wo, wob);
    cvt_f2bf<<<4096, 256, 0, stream>>>(fc1w, wf1);
    cvt_f2bf<<<4096, 256, 0, stream>>>(fc2w, wf2);

    ln_kernel<<<MTOK, 256, 0, stream>>>(hidden, ln1w, ln1b, xln);

    gemm_bt<0><<<dim3(8,65), 256, 0, stream>>>(xln, wqb, bq, nullptr, nullptr, qbuf, 1024, 1024, MTOK, QSCALE);
    gemm_bt<0><<<dim3(8,65), 256, 0, stream>>>(xln, wkb, bk, nullptr, nullptr, kbuf, 1024, 1024, MTOK, 1.0f);
    gemm_bt<0><<<dim3(8,65), 256, 0, stream>>>(xln, wvb, bv, nullptr, nullptr, vbuf, 1024, 1024, MTOK, 1.0f);

    attn_kernel<<<dim3(512,5), 256, 0, stream>>>(qbuf, kbuf, vbuf, out0, ctxb, out2);

    gemm_bt<1><<<dim3(8,65), 256, 0, stream>>>(ctxb, wob, bo, hidden, hbuf, nullptr, 1024, 1024, MTOK, 1.0f);

    ln_kernel<<<MTOK, 256, 0, stream>>>(hbuf, ln2w, ln2b, xln);

    gemm_bt<2><<<dim3(32,65), 256, 0, stream>>>(xln, wf1, fc1b, nullptr, nullptr, fc1o, 1024, 4096, MTOK, 1.0f);
    gemm_bt<1><<<dim3(8,65), 256, 0, stream>>>(fc1o, wf2, fc2b, hbuf, out1, nullptr, 4096, 1024, MTOK, 1.0f);
}